// Round 4
// baseline (128.647 us; speedup 1.0000x reference)
//
#include <hip/hip_runtime.h>
#include <math.h>

#define D 768
#define T 128
#define KC 16            // split-K chunks for GEMM1
#define CHUNKK (D / KC)  // 48
#define NSUB (CHUNKK / 16) // 3 sub-chunks of 16
#define NBLK 192

// ln(0.9*0.99) = ln(0.891)
#define LN_ETA_DECAY (-0.11541085151132775f)

// ---------------------------------------------------------------------------
// Single regular-launch pipeline kernel, 192 blocks x 512 threads.
//   Stage A (all blocks): split-K GEMM1 chunk  P = keys @ W^T  (o-tile bx,
//     k-chunk by). Arrival: threadfence + atomicAdd(done[bx]). The 16th
//     arriver reduces its o-tile: errW = sum_kc Ppart - values, then
//     threadfence + flag[bx]=1 (release).
//   Stage B (blocks 0..143): k2 block (oT=b/12, iT=b%12). Pre-stages
//     sKs/sC/sB0 + mW/W register prefetch BEFORE polling flag[oT]
//     (relaxed poll + s_sleep backoff, ONE acquire after exit), then
//     stages sErr and runs GEMM2 + fused W/mW/b epilogue.
//   Block 191: waits for all 12 flags, computes losses from errW directly
//     (plain stores - no atomics, no zero-init needed).
// Per-o-tile flags instead of grid barriers: ~13 acquire-invalidates total
// vs R3's per-poll acquires (the ~18us/barrier pathology).
// Deadlock-safe: 66KB LDS -> >=2 blocks/CU capacity -> all 192 blocks
// resident under any packing; producers never wait.
// d_ws[0..8KB) = sync slots (memset'd in-stream each iteration).
// ---------------------------------------------------------------------------

union SharedU {
    struct {
        float sKt[16][132];  // [k][t], pitch 132
        float sWo[16][68];   // [k][o], pitch 68
    } p1;
    struct {
        float sErr[T][64];   // errW[t, o-local]
        float sKs[T][64];    // 2*c[t]*keys[t, i-local]
        float sC[T];         // c[t]
        float sB0[64];       // bparam[o-local]
    } p3;
};

__global__ __launch_bounds__(512) void pipeline(
    const float* __restrict__ W,
    const float* __restrict__ keys,
    const float* __restrict__ values,
    const float* __restrict__ mW,
    const float* __restrict__ bparam,
    const float* __restrict__ mb,
    float* __restrict__ W_new,
    float* __restrict__ b_new,
    float* __restrict__ mW_new,
    float* __restrict__ mb_new,
    float* __restrict__ losses,
    int* __restrict__ syncb,     // done[i]=syncb[i*64], flag[i]=syncb[768+i*64]
    float* __restrict__ Ppart,
    float* __restrict__ errW,
    float pow_eta_T, float beta_total, float Csum)
{
    __shared__ SharedU sh;
    __shared__ int sLast;

    const int b = blockIdx.x;
    const int tid = threadIdx.x;
    const int bx = b >> 4;          // producer o-tile 0..11
    const int by = b & 15;          // producer k-chunk 0..15
    const int p_obase = bx * 64;

    // =====================================================================
    // Stage A: split-K partial GEMM chunk (proven R2/R3 code, 512 thr)
    // =====================================================================
    {
        float (&sKt)[16][132] = sh.p1.sKt;
        float (&sWo)[16][68]  = sh.p1.sWo;

        const int kbase = by * CHUNKK;
        const int ty = tid >> 4;        // t-group (4 t's), 0..31
        const int tx = tid & 15;        // o-group (4 o's)
        const int t0 = tid >> 2;        // keys staging row (0..127)
        const int q0 = tid & 3;         // staging float4-col (0..3)
        const int o0 = (tid >> 2) & 63; // W staging row for tid<256

        float acc[4][4];
        #pragma unroll
        for (int j = 0; j < 4; ++j)
            #pragma unroll
            for (int n = 0; n < 4; ++n) acc[j][n] = 0.f;

        float4 gk = *reinterpret_cast<const float4*>(keys + t0 * D + kbase + q0 * 4);
        float4 gw;
        if (tid < 256)
            gw = *reinterpret_cast<const float4*>(W + (p_obase + o0) * D + kbase + q0 * 4);

        for (int c = 0; c < NSUB; ++c) {
            sKt[q0 * 4 + 0][t0] = gk.x;
            sKt[q0 * 4 + 1][t0] = gk.y;
            sKt[q0 * 4 + 2][t0] = gk.z;
            sKt[q0 * 4 + 3][t0] = gk.w;
            if (tid < 256) {
                sWo[q0 * 4 + 0][o0] = gw.x;
                sWo[q0 * 4 + 1][o0] = gw.y;
                sWo[q0 * 4 + 2][o0] = gw.z;
                sWo[q0 * 4 + 3][o0] = gw.w;
            }
            __syncthreads();

            if (c + 1 < NSUB) {
                const int kb = kbase + (c + 1) * 16;
                gk = *reinterpret_cast<const float4*>(keys + t0 * D + kb + q0 * 4);
                if (tid < 256)
                    gw = *reinterpret_cast<const float4*>(W + (p_obase + o0) * D + kb + q0 * 4);
            }

            #pragma unroll
            for (int k = 0; k < 16; ++k) {
                float4 a = *reinterpret_cast<const float4*>(&sKt[k][ty * 4]);
                float4 bb = *reinterpret_cast<const float4*>(&sWo[k][tx * 4]);
                const float av[4] = { a.x, a.y, a.z, a.w };
                const float bv[4] = { bb.x, bb.y, bb.z, bb.w };
                #pragma unroll
                for (int j = 0; j < 4; ++j)
                    #pragma unroll
                    for (int n = 0; n < 4; ++n) acc[j][n] += av[j] * bv[n];
            }
            __syncthreads();
        }

        float* outp = Ppart + by * (T * D);
        #pragma unroll
        for (int j = 0; j < 4; ++j) {
            const int t = ty * 4 + j;
            float4 v = { acc[j][0], acc[j][1], acc[j][2], acc[j][3] };
            *reinterpret_cast<float4*>(outp + t * D + p_obase + tx * 4) = v;
        }
    }

    // ---- arrival: release own chunk, detect last arriver ----
    __syncthreads();   // compiler drains vmcnt before barrier -> stores done
    if (tid == 0) {
        __threadfence();   // agent-scope release (writeback)
        int old = __hip_atomic_fetch_add(&syncb[bx * 64], 1,
                     __ATOMIC_ACQ_REL, __HIP_MEMORY_SCOPE_AGENT);
        sLast = (old == KC - 1);
    }
    __syncthreads();

    if (sLast) {
        // last arriver reduces this o-tile: errW = sum_kc Ppart - values
        if (tid == 0) __threadfence();   // acquire: see peers' chunks
        __syncthreads();
        #pragma unroll
        for (int r = 0; r < 4; ++r) {
            const int idx = tid + r * 512;         // 0..2047 float4s of tile
            const int t = idx >> 4, q = idx & 15;
            const int off = t * D + p_obase + q * 4;
            float4 vv = *reinterpret_cast<const float4*>(values + off);
            float4 s = { -vv.x, -vv.y, -vv.z, -vv.w };
            #pragma unroll
            for (int kc = 0; kc < KC; ++kc) {
                float4 v = *reinterpret_cast<const float4*>(Ppart + kc * (T * D) + off);
                s.x += v.x; s.y += v.y; s.z += v.z; s.w += v.w;
            }
            *reinterpret_cast<float4*>(errW + off) = s;
        }
        __syncthreads();
        if (tid == 0) {
            __threadfence();   // release errW
            __hip_atomic_store(&syncb[768 + bx * 64], 1,
                               __ATOMIC_RELEASE, __HIP_MEMORY_SCOPE_AGENT);
        }
    }

    // =====================================================================
    // Stage B: k2 consumer blocks (0..143)
    // =====================================================================
    if (b < 144) {
        float (&sErr)[T][64] = sh.p3.sErr;
        float (&sKs)[T][64]  = sh.p3.sKs;
        float (&sC)[T]       = sh.p3.sC;
        float (&sB0)[64]     = sh.p3.sB0;

        const int oT = b / 12, iT = b % 12;
        const int obase = oT * 64, ibase = iT * 64;
        const int ty = tid >> 4, tx = tid & 15;   // (tid<256) o-group, i-group

        // ---- pre-stage everything errW-independent BEFORE the poll ----
        float4 pm[4], pw[4];
        if (tid < 256) {
            #pragma unroll
            for (int aa = 0; aa < 4; ++aa) {
                const int o = obase + ty * 4 + aa;
                const int i = ibase + tx * 4;
                pm[aa] = *reinterpret_cast<const float4*>(mW + o * D + i);
                pw[aa] = *reinterpret_cast<const float4*>(W + o * D + i);
            }
        }
        if (tid < T)  sC[tid]  = 0.01f * __expf((float)(127 - tid) * LN_ETA_DECAY);
        if (tid < 64) sB0[tid] = bparam[obase + tid];

        #pragma unroll
        for (int r = 0; r < 4; ++r) {
            const int idx = tid + r * 512;
            const int t = idx >> 4, q = idx & 15;
            const float c2 = 2.f * 0.01f * __expf((float)(127 - t) * LN_ETA_DECAY);
            float4 kv = *reinterpret_cast<const float4*>(keys + t * D + ibase + q * 4);
            kv.x *= c2; kv.y *= c2; kv.z *= c2; kv.w *= c2;
            *reinterpret_cast<float4*>(&sKs[t][q * 4]) = kv;
        }

        // ---- wait for this o-tile's errW: relaxed poll, ONE acquire ----
        if (tid == 0) {
            while (__hip_atomic_load(&syncb[768 + oT * 64],
                     __ATOMIC_RELAXED, __HIP_MEMORY_SCOPE_AGENT) == 0)
                __builtin_amdgcn_s_sleep(4);
            (void)__hip_atomic_load(&syncb[768 + oT * 64],
                     __ATOMIC_ACQUIRE, __HIP_MEMORY_SCOPE_AGENT);
        }
        __syncthreads();

        // ---- stage sErr from errW ----
        #pragma unroll
        for (int r = 0; r < 4; ++r) {
            const int idx = tid + r * 512;
            const int t = idx >> 4, q = idx & 15;
            float4 ev = *reinterpret_cast<const float4*>(errW + t * D + obase + q * 4);
            *reinterpret_cast<float4*>(&sErr[t][q * 4]) = ev;
        }
        __syncthreads();

        // ---- GEMM2 + W/mW epilogue (threads 0..255) ----
        if (tid < 256) {
            float acc[4][4];
            #pragma unroll
            for (int a = 0; a < 4; ++a)
                #pragma unroll
                for (int n = 0; n < 4; ++n) acc[a][n] = 0.f;

            #pragma unroll 4
            for (int t = 0; t < T; ++t) {
                float4 a = *reinterpret_cast<const float4*>(&sErr[t][ty * 4]);
                float4 bb = *reinterpret_cast<const float4*>(&sKs[t][tx * 4]);
                const float av[4] = { a.x, a.y, a.z, a.w };
                const float bv[4] = { bb.x, bb.y, bb.z, bb.w };
                #pragma unroll
                for (int aa = 0; aa < 4; ++aa)
                    #pragma unroll
                    for (int nn = 0; nn < 4; ++nn) acc[aa][nn] += av[aa] * bv[nn];
            }

            #pragma unroll
            for (int aa = 0; aa < 4; ++aa) {
                const int o = obase + ty * 4 + aa;
                const int i = ibase + tx * 4;
                float4 nm, wn;
                nm.x = pow_eta_T * pm[aa].x - acc[aa][0];
                nm.y = pow_eta_T * pm[aa].y - acc[aa][1];
                nm.z = pow_eta_T * pm[aa].z - acc[aa][2];
                nm.w = pow_eta_T * pm[aa].w - acc[aa][3];
                wn.x = beta_total * pw[aa].x + nm.x;
                wn.y = beta_total * pw[aa].y + nm.y;
                wn.z = beta_total * pw[aa].z + nm.z;
                wn.w = beta_total * pw[aa].w + nm.w;
                *reinterpret_cast<float4*>(mW_new + o * D + i) = nm;
                *reinterpret_cast<float4*>(W_new + o * D + i) = wn;
            }
        }

        // ---- b epilogue (once per o-tile) ----
        if (iT == 0 && tid < 64) {
            float S = 0.f;
            for (int t = 0; t < T; ++t) S += sC[t] * sErr[t][tid];
            const int o = obase + tid;
            const float nmb = pow_eta_T * mb[o] - 2.f * S - 2.f * Csum * sB0[tid];
            mb_new[o] = nmb;
            b_new[o]  = beta_total * sB0[tid] + nmb;
        }
    }
    else if (b == 191) {
        // ---- losses from errW directly (plain stores, no atomics) ----
        if (tid == 0) {
            for (int f = 0; f < 12; ++f)
                while (__hip_atomic_load(&syncb[768 + f * 64],
                         __ATOMIC_RELAXED, __HIP_MEMORY_SCOPE_AGENT) == 0)
                    __builtin_amdgcn_s_sleep(8);
            (void)__hip_atomic_load(&syncb[768],
                     __ATOMIC_ACQUIRE, __HIP_MEMORY_SCOPE_AGENT);
        }
        __syncthreads();
        const int t = tid >> 2, seg = tid & 3;     // 128 t x 4 segments of 192
        const float* er = errW + t * D + seg * 192;
        const float* bp = bparam + seg * 192;
        float L = 0.f;
        #pragma unroll 8
        for (int oo = 0; oo < 192; oo += 4) {
            float4 e  = *reinterpret_cast<const float4*>(er + oo);
            float4 bb = *reinterpret_cast<const float4*>(bp + oo);
            const float a0 = e.x + bb.x, a1 = e.y + bb.y;
            const float a2 = e.z + bb.z, a3 = e.w + bb.w;
            L += a0 * a0 + a1 * a1 + a2 * a2 + a3 * a3;
        }
        L += __shfl_xor(L, 1, 64);
        L += __shfl_xor(L, 2, 64);
        if (seg == 0) losses[t] = L * (1.f / 768.f);
    }
}

extern "C" void kernel_launch(void* const* d_in, const int* in_sizes, int n_in,
                              void* d_out, int out_size, void* d_ws, size_t ws_size,
                              hipStream_t stream) {
    const float* W      = (const float*)d_in[0];
    const float* bparam = (const float*)d_in[1];
    const float* keys   = (const float*)d_in[2];
    const float* values = (const float*)d_in[3];
    const float* mW     = (const float*)d_in[4];
    const float* mb     = (const float*)d_in[5];

    float* out = (float*)d_out;
    float* W_new  = out;               // 768*768
    float* b_new  = out + 589824;      // 768
    float* mW_new = out + 590592;      // 768*768
    float* mb_new = out + 1180416;     // 768
    float* losses = out + 1181184;     // 128

    int*   syncb = (int*)d_ws;                           // 8 KB sync region
    float* Ppart = (float*)((char*)d_ws + 8192);         // KC*T*D floats
    float* errW  = Ppart + KC * T * D;                   // T*D floats

    double cs = 0.0;
    for (int t = 0; t < T; ++t) cs += 0.01 * pow(0.891, 127 - t);
    const float pow_eta_T  = (float)pow(0.9, 128);
    const float beta_total = (float)pow(0.99, 128);
    const float Csum = (float)cs;

    // sync slots start poisoned every iteration -> zero them in-stream
    hipMemsetAsync(d_ws, 0, 8192, stream);
    pipeline<<<NBLK, 512, 0, stream>>>(W, keys, values, mW, bparam, mb,
                                       W_new, b_new, mW_new, mb_new, losses,
                                       syncb, Ppart, errW,
                                       pow_eta_T, beta_total, Csum);
}

// Round 5
// 93.416 us; speedup vs baseline: 1.3771x; 1.3771x over previous
//
#include <hip/hip_runtime.h>
#include <math.h>

#define D 768
#define T 128
#define KC 16            // split-K chunks for GEMM1
#define CHUNKK (D / KC)  // 48
#define NSUB (CHUNKK / 16) // 3 sub-chunks of 16

// ln(0.9*0.99) = ln(0.891)
#define LN_ETA_DECAY (-0.11541085151132775f)

// ---------------------------------------------------------------------------
// K1: split-K partial GEMM  P = keys @ W^T   (M=128 t, N=768 o, K=768)
// grid = (12 o-tiles, KC=16 k-chunks), 512 threads. Per-thread tile 4t x 4o.
// Ppart layout [oTile][kc][t][64]: each block stores one contiguous 32 KB
// tile (and k2 reads contiguous streams). Block (0,0) zeroes losses
// (k2's atomic target; ordered by the kernel boundary).
// ---------------------------------------------------------------------------
__global__ __launch_bounds__(512) void k1_pgemm(
    const float* __restrict__ W,
    const float* __restrict__ keys,
    float* __restrict__ Ppart,
    float* __restrict__ losses)
{
    __shared__ float sKt[16][132];  // [k][t], pitch 132
    __shared__ float sWo[16][68];   // [k][o], pitch 68

    const int bx = blockIdx.x;      // o-tile 0..11
    const int by = blockIdx.y;      // k-chunk 0..15
    const int obase = bx * 64;
    const int kbase = by * CHUNKK;
    const int tid = threadIdx.x;
    const int ty = tid >> 4;        // t-group (4 t's), 0..31
    const int tx = tid & 15;        // o-group (4 o's)
    const int t0 = tid >> 2;        // keys staging row (0..127)
    const int q0 = tid & 3;         // staging float4-col (0..3)
    const int o0 = (tid >> 2) & 63; // W staging row for tid<256

    if (bx == 0 && by == 0 && tid < T) losses[tid] = 0.f;

    float acc[4][4];
    #pragma unroll
    for (int j = 0; j < 4; ++j)
        #pragma unroll
        for (int n = 0; n < 4; ++n) acc[j][n] = 0.f;

    // prologue: load sub-chunk 0 into regs
    float4 gk = *reinterpret_cast<const float4*>(keys + t0 * D + kbase + q0 * 4);
    float4 gw;
    if (tid < 256)
        gw = *reinterpret_cast<const float4*>(W + (obase + o0) * D + kbase + q0 * 4);

    for (int c = 0; c < NSUB; ++c) {
        // regs -> LDS (transposed to k-major)
        sKt[q0 * 4 + 0][t0] = gk.x;
        sKt[q0 * 4 + 1][t0] = gk.y;
        sKt[q0 * 4 + 2][t0] = gk.z;
        sKt[q0 * 4 + 3][t0] = gk.w;
        if (tid < 256) {
            sWo[q0 * 4 + 0][o0] = gw.x;
            sWo[q0 * 4 + 1][o0] = gw.y;
            sWo[q0 * 4 + 2][o0] = gw.z;
            sWo[q0 * 4 + 3][o0] = gw.w;
        }
        __syncthreads();

        // issue NEXT sub-chunk's loads (consumed at next iteration's store)
        if (c + 1 < NSUB) {
            const int kb = kbase + (c + 1) * 16;
            gk = *reinterpret_cast<const float4*>(keys + t0 * D + kb + q0 * 4);
            if (tid < 256)
                gw = *reinterpret_cast<const float4*>(W + (obase + o0) * D + kb + q0 * 4);
        }

        #pragma unroll
        for (int k = 0; k < 16; ++k) {
            float4 a = *reinterpret_cast<const float4*>(&sKt[k][ty * 4]);
            float4 b = *reinterpret_cast<const float4*>(&sWo[k][tx * 4]);
            const float av[4] = { a.x, a.y, a.z, a.w };
            const float bv[4] = { b.x, b.y, b.z, b.w };
            #pragma unroll
            for (int j = 0; j < 4; ++j)
                #pragma unroll
                for (int n = 0; n < 4; ++n) acc[j][n] += av[j] * bv[n];
        }
        __syncthreads();
    }

    // contiguous 32 KB tile: Ppart[bx][by][t][0..63]
    float* outp = Ppart + (bx * KC + by) * (T * 64);
    #pragma unroll
    for (int j = 0; j < 4; ++j) {
        const int t = ty * 4 + j;
        float4 v = { acc[j][0], acc[j][1], acc[j][2], acc[j][3] };
        *reinterpret_cast<float4*>(outp + t * 64 + tx * 4) = v;
    }
}

// ---------------------------------------------------------------------------
// K2: fused reduce + GEMM2 + epilogues. 144 blocks (12 oT x 12 iT), 512 thr.
// Stages sErr by reducing Ppart[oT][kc] over kc and subtracting values
// (absorbs the old k15 kernel: one less dispatch + dependency edge; the
// 12 i-tile blocks of an o-tile redundantly read the same 512 KB, which is
// L2/IF$-resident). Then GEMM2 G = errW^T @ (2c*keys) with the mW/W
// register-prefetched epilogue; iT==0 emits b_new/mb_new; iT==1 adds loss
// partials (losses zeroed by k1).
// ---------------------------------------------------------------------------
__global__ __launch_bounds__(512) void k2_main(
    const float* __restrict__ Ppart,
    const float* __restrict__ values,
    const float* __restrict__ keys,
    const float* __restrict__ W,
    const float* __restrict__ mW,
    const float* __restrict__ bparam,
    const float* __restrict__ mb,
    float* __restrict__ W_new,
    float* __restrict__ b_new,
    float* __restrict__ mW_new,
    float* __restrict__ mb_new,
    float* __restrict__ losses,
    float pow_eta_T, float beta_total, float Csum)
{
    __shared__ float sErr[T][64];   // errW[t, o-local]
    __shared__ float sKs[T][64];    // 2*c[t]*keys[t, i-local]
    __shared__ float sC[T];         // c[t]
    __shared__ float sB0[64];       // bparam[o-local]

    const int oT = blockIdx.x / 12, iT = blockIdx.x % 12;
    const int obase = oT * 64, ibase = iT * 64;
    const int tid = threadIdx.x;
    const int ty = tid >> 4, tx = tid & 15;   // (tid<256) o-group, i-group

    // ---- epilogue prefetch: issue mW/W loads NOW, consume after GEMM2 ----
    float4 pm[4], pw[4];
    if (tid < 256) {
        #pragma unroll
        for (int aa = 0; aa < 4; ++aa) {
            const int o = obase + ty * 4 + aa;
            const int i = ibase + tx * 4;
            pm[aa] = *reinterpret_cast<const float4*>(mW + o * D + i);
            pw[aa] = *reinterpret_cast<const float4*>(W + o * D + i);
        }
    }

    if (tid < T)  sC[tid]  = 0.01f * __expf((float)(127 - tid) * LN_ETA_DECAY);
    if (tid < 64) sB0[tid] = bparam[obase + tid];

    // ---- stage sKs = 2*c[t]*keys[t, i-tile] ----
    #pragma unroll
    for (int r = 0; r < 4; ++r) {
        const int idx = tid + r * 512;
        const int t = idx >> 4, q = idx & 15;
        const float c2 = 2.f * 0.01f * __expf((float)(127 - t) * LN_ETA_DECAY);
        float4 kv = *reinterpret_cast<const float4*>(keys + t * D + ibase + q * 4);
        kv.x *= c2; kv.y *= c2; kv.z *= c2; kv.w *= c2;
        *reinterpret_cast<float4*>(&sKs[t][q * 4]) = kv;
    }

    // ---- stage sErr = sum_kc Ppart[oT][kc] - values (fused k15) ----
    const float* Pp = Ppart + oT * (KC * T * 64);
    #pragma unroll
    for (int r = 0; r < 4; ++r) {
        const int idx = tid + r * 512;
        const int t = idx >> 4, q = idx & 15;
        float4 vv = *reinterpret_cast<const float4*>(values + t * D + obase + q * 4);
        float4 s = { -vv.x, -vv.y, -vv.z, -vv.w };
        #pragma unroll
        for (int kc = 0; kc < KC; ++kc) {
            float4 v = *reinterpret_cast<const float4*>(Pp + kc * (T * 64) + t * 64 + q * 4);
            s.x += v.x; s.y += v.y; s.z += v.z; s.w += v.w;
        }
        *reinterpret_cast<float4*>(&sErr[t][q * 4]) = s;
    }
    __syncthreads();

    // ---- GEMM2 + W/mW epilogue (threads 0..255) ----
    if (tid < 256) {
        float acc[4][4];
        #pragma unroll
        for (int a = 0; a < 4; ++a)
            #pragma unroll
            for (int n = 0; n < 4; ++n) acc[a][n] = 0.f;

        #pragma unroll 4
        for (int t = 0; t < T; ++t) {
            float4 a = *reinterpret_cast<const float4*>(&sErr[t][ty * 4]);
            float4 b = *reinterpret_cast<const float4*>(&sKs[t][tx * 4]);
            const float av[4] = { a.x, a.y, a.z, a.w };
            const float bv[4] = { b.x, b.y, b.z, b.w };
            #pragma unroll
            for (int aa = 0; aa < 4; ++aa)
                #pragma unroll
                for (int bb = 0; bb < 4; ++bb) acc[aa][bb] += av[aa] * bv[bb];
        }

        #pragma unroll
        for (int aa = 0; aa < 4; ++aa) {
            const int o = obase + ty * 4 + aa;
            const int i = ibase + tx * 4;
            float4 nm, wn;
            nm.x = pow_eta_T * pm[aa].x - acc[aa][0];
            nm.y = pow_eta_T * pm[aa].y - acc[aa][1];
            nm.z = pow_eta_T * pm[aa].z - acc[aa][2];
            nm.w = pow_eta_T * pm[aa].w - acc[aa][3];
            wn.x = beta_total * pw[aa].x + nm.x;
            wn.y = beta_total * pw[aa].y + nm.y;
            wn.z = beta_total * pw[aa].z + nm.z;
            wn.w = beta_total * pw[aa].w + nm.w;
            *reinterpret_cast<float4*>(mW_new + o * D + i) = nm;
            *reinterpret_cast<float4*>(W_new + o * D + i) = wn;
        }
    }

    // ---- b epilogue (once per o-tile) ----
    if (iT == 0 && tid < 64) {
        float S = 0.f;
        for (int t = 0; t < T; ++t) S += sC[t] * sErr[t][tid];
        const int o = obase + tid;
        const float nmb = pow_eta_T * mb[o] - 2.f * S - 2.f * Csum * sB0[tid];
        mb_new[o] = nmb;
        b_new[o]  = beta_total * sB0[tid] + nmb;
    }

    // ---- losses partial (once per o-tile); losses zeroed by k1 ----
    if (iT == 1 && tid < 256) {
        const int t = tid >> 1, h = tid & 1;
        float L = 0.f;
        #pragma unroll 8
        for (int oo = 0; oo < 32; ++oo) {
            const int o = ((h * 32 + oo) + t) & 63;   // skew to dodge bank aliasing
            const float e = sErr[t][o] + sB0[o];
            L += e * e;
        }
        L += __shfl_xor(L, 1, 64);
        if (h == 0) atomicAdd(losses + t, L * (1.f / 768.f));
    }
}

extern "C" void kernel_launch(void* const* d_in, const int* in_sizes, int n_in,
                              void* d_out, int out_size, void* d_ws, size_t ws_size,
                              hipStream_t stream) {
    const float* W      = (const float*)d_in[0];
    const float* bparam = (const float*)d_in[1];
    const float* keys   = (const float*)d_in[2];
    const float* values = (const float*)d_in[3];
    const float* mW     = (const float*)d_in[4];
    const float* mb     = (const float*)d_in[5];

    float* out = (float*)d_out;
    float* W_new  = out;               // 768*768
    float* b_new  = out + 589824;      // 768
    float* mW_new = out + 590592;      // 768*768
    float* mb_new = out + 1180416;     // 768
    float* losses = out + 1181184;     // 128

    float* Ppart = (float*)d_ws;       // [12][16][128][64] floats = 6.3 MB

    double cs = 0.0;
    for (int t = 0; t < T; ++t) cs += 0.01 * pow(0.891, 127 - t);
    const float pow_eta_T  = (float)pow(0.9, 128);
    const float beta_total = (float)pow(0.99, 128);
    const float Csum = (float)cs;

    k1_pgemm<<<dim3(12, KC), 512, 0, stream>>>(W, keys, Ppart, losses);
    k2_main<<<144, 512, 0, stream>>>(Ppart, values, keys, W, mW, bparam, mb,
                                     W_new, b_new, mW_new, mb_new, losses,
                                     pow_eta_T, beta_total, Csum);
}

// Round 6
// 87.514 us; speedup vs baseline: 1.4700x; 1.0674x over previous
//
#include <hip/hip_runtime.h>
#include <math.h>

#define D 768
#define T 128
#define KC 8             // split-K chunks for GEMM1 (k1 VALU vs k2 reduce balance)
#define CHUNKK (D / KC)  // 96
#define NSUB (CHUNKK / 16) // 6 sub-chunks of 16

// ln(0.9*0.99) = ln(0.891)
#define LN_ETA_DECAY (-0.11541085151132775f)

// ---------------------------------------------------------------------------
// K1: split-K partial GEMM  P = keys @ W^T   (M=128 t, N=768 o, K=768)
// grid = (12 o-tiles, KC=8 k-chunks) = 96 blocks, 512 threads.
// Per-thread tile 4t x 4o, K-chunk 96 (6 staged sub-chunks of 16).
// Ppart layout [oTile][kc][t][64]: each block stores one contiguous 32 KB
// tile; k2 reads contiguous streams. KC=8 (not 16) halves k2's redundant
// reduce traffic (37 MB vs 73 MB) at +1.3 us of k1 VALU time - the minimum
// of the summed cost curve. Block (0,0) zeroes losses (k2's atomic target).
// ---------------------------------------------------------------------------
__global__ __launch_bounds__(512) void k1_pgemm(
    const float* __restrict__ W,
    const float* __restrict__ keys,
    float* __restrict__ Ppart,
    float* __restrict__ losses)
{
    __shared__ float sKt[16][132];  // [k][t], pitch 132
    __shared__ float sWo[16][68];   // [k][o], pitch 68

    const int bx = blockIdx.x;      // o-tile 0..11
    const int by = blockIdx.y;      // k-chunk 0..7
    const int obase = bx * 64;
    const int kbase = by * CHUNKK;
    const int tid = threadIdx.x;
    const int ty = tid >> 4;        // t-group (4 t's), 0..31
    const int tx = tid & 15;        // o-group (4 o's)
    const int t0 = tid >> 2;        // keys staging row (0..127)
    const int q0 = tid & 3;         // staging float4-col (0..3)
    const int o0 = (tid >> 2) & 63; // W staging row for tid<256

    if (bx == 0 && by == 0 && tid < T) losses[tid] = 0.f;

    float acc[4][4];
    #pragma unroll
    for (int j = 0; j < 4; ++j)
        #pragma unroll
        for (int n = 0; n < 4; ++n) acc[j][n] = 0.f;

    // prologue: load sub-chunk 0 into regs
    float4 gk = *reinterpret_cast<const float4*>(keys + t0 * D + kbase + q0 * 4);
    float4 gw;
    if (tid < 256)
        gw = *reinterpret_cast<const float4*>(W + (obase + o0) * D + kbase + q0 * 4);

    for (int c = 0; c < NSUB; ++c) {
        // regs -> LDS (transposed to k-major)
        sKt[q0 * 4 + 0][t0] = gk.x;
        sKt[q0 * 4 + 1][t0] = gk.y;
        sKt[q0 * 4 + 2][t0] = gk.z;
        sKt[q0 * 4 + 3][t0] = gk.w;
        if (tid < 256) {
            sWo[q0 * 4 + 0][o0] = gw.x;
            sWo[q0 * 4 + 1][o0] = gw.y;
            sWo[q0 * 4 + 2][o0] = gw.z;
            sWo[q0 * 4 + 3][o0] = gw.w;
        }
        __syncthreads();

        // issue NEXT sub-chunk's loads (consumed at next iteration's store)
        if (c + 1 < NSUB) {
            const int kb = kbase + (c + 1) * 16;
            gk = *reinterpret_cast<const float4*>(keys + t0 * D + kb + q0 * 4);
            if (tid < 256)
                gw = *reinterpret_cast<const float4*>(W + (obase + o0) * D + kb + q0 * 4);
        }

        #pragma unroll
        for (int k = 0; k < 16; ++k) {
            float4 a = *reinterpret_cast<const float4*>(&sKt[k][ty * 4]);
            float4 b = *reinterpret_cast<const float4*>(&sWo[k][tx * 4]);
            const float av[4] = { a.x, a.y, a.z, a.w };
            const float bv[4] = { b.x, b.y, b.z, b.w };
            #pragma unroll
            for (int j = 0; j < 4; ++j)
                #pragma unroll
                for (int n = 0; n < 4; ++n) acc[j][n] += av[j] * bv[n];
        }
        __syncthreads();
    }

    // contiguous 32 KB tile: Ppart[bx][by][t][0..63]
    float* outp = Ppart + (bx * KC + by) * (T * 64);
    #pragma unroll
    for (int j = 0; j < 4; ++j) {
        const int t = ty * 4 + j;
        float4 v = { acc[j][0], acc[j][1], acc[j][2], acc[j][3] };
        *reinterpret_cast<float4*>(outp + t * 64 + tx * 4) = v;
    }
}

// ---------------------------------------------------------------------------
// K2: fused reduce + GEMM2 + epilogues. 144 blocks (12 oT x 12 iT), 512 thr.
// Stages sErr by reducing Ppart[oT][kc] over the 8 k-chunks and subtracting
// values (absorbs the old k15 kernel). Then GEMM2 G = errW^T @ (2c*keys)
// using ALL 512 threads (2o x 4i per thread), with mW/W register-prefetched
// epilogue; iT==0 emits b_new/mb_new; iT==1 adds loss partials.
// ---------------------------------------------------------------------------
__global__ __launch_bounds__(512) void k2_main(
    const float* __restrict__ Ppart,
    const float* __restrict__ values,
    const float* __restrict__ keys,
    const float* __restrict__ W,
    const float* __restrict__ mW,
    const float* __restrict__ bparam,
    const float* __restrict__ mb,
    float* __restrict__ W_new,
    float* __restrict__ b_new,
    float* __restrict__ mW_new,
    float* __restrict__ mb_new,
    float* __restrict__ losses,
    float pow_eta_T, float beta_total, float Csum)
{
    __shared__ float sErr[T][64];   // errW[t, o-local]
    __shared__ float sKs[T][64];    // 2*c[t]*keys[t, i-local]
    __shared__ float sC[T];         // c[t]
    __shared__ float sB0[64];       // bparam[o-local]

    const int oT = blockIdx.x / 12, iT = blockIdx.x % 12;
    const int obase = oT * 64, ibase = iT * 64;
    const int tid = threadIdx.x;
    const int ty = tid >> 4;   // 0..31, owns o-pair ty*2
    const int tx = tid & 15;   // i-quad

    // ---- epilogue prefetch: issue mW/W loads NOW, consume after GEMM2 ----
    float4 pm[2], pw[2];
    #pragma unroll
    for (int aa = 0; aa < 2; ++aa) {
        const int o = obase + ty * 2 + aa;
        const int i = ibase + tx * 4;
        pm[aa] = *reinterpret_cast<const float4*>(mW + o * D + i);
        pw[aa] = *reinterpret_cast<const float4*>(W + o * D + i);
    }

    if (tid < T)  sC[tid]  = 0.01f * __expf((float)(127 - tid) * LN_ETA_DECAY);
    if (tid < 64) sB0[tid] = bparam[obase + tid];

    // ---- stage sKs = 2*c[t]*keys[t, i-tile] ----
    #pragma unroll
    for (int r = 0; r < 4; ++r) {
        const int idx = tid + r * 512;
        const int t = idx >> 4, q = idx & 15;
        const float c2 = 2.f * 0.01f * __expf((float)(127 - t) * LN_ETA_DECAY);
        float4 kv = *reinterpret_cast<const float4*>(keys + t * D + ibase + q * 4);
        kv.x *= c2; kv.y *= c2; kv.z *= c2; kv.w *= c2;
        *reinterpret_cast<float4*>(&sKs[t][q * 4]) = kv;
    }

    // ---- stage sErr = sum_kc Ppart[oT][kc] - values (fused k15) ----
    const float* Pp = Ppart + oT * (KC * T * 64);
    #pragma unroll
    for (int r = 0; r < 4; ++r) {
        const int idx = tid + r * 512;
        const int t = idx >> 4, q = idx & 15;
        float4 vv = *reinterpret_cast<const float4*>(values + t * D + obase + q * 4);
        float4 s = { -vv.x, -vv.y, -vv.z, -vv.w };
        #pragma unroll
        for (int kc = 0; kc < KC; ++kc) {
            float4 v = *reinterpret_cast<const float4*>(Pp + kc * (T * 64) + t * 64 + q * 4);
            s.x += v.x; s.y += v.y; s.z += v.z; s.w += v.w;
        }
        *reinterpret_cast<float4*>(&sErr[t][q * 4]) = s;
    }
    __syncthreads();

    // ---- GEMM2: all 512 threads, per-thread 2o x 4i ----
    float acc[2][4];
    #pragma unroll
    for (int a = 0; a < 2; ++a)
        #pragma unroll
        for (int n = 0; n < 4; ++n) acc[a][n] = 0.f;

    #pragma unroll 4
    for (int t = 0; t < T; ++t) {
        float2 a = *reinterpret_cast<const float2*>(&sErr[t][ty * 2]);
        float4 b = *reinterpret_cast<const float4*>(&sKs[t][tx * 4]);
        const float av[2] = { a.x, a.y };
        const float bv[4] = { b.x, b.y, b.z, b.w };
        #pragma unroll
        for (int aa = 0; aa < 2; ++aa)
            #pragma unroll
            for (int nn = 0; nn < 4; ++nn) acc[aa][nn] += av[aa] * bv[nn];
    }

    // ---- W / mW epilogue from prefetched regs ----
    #pragma unroll
    for (int aa = 0; aa < 2; ++aa) {
        const int o = obase + ty * 2 + aa;
        const int i = ibase + tx * 4;
        float4 nm, wn;
        nm.x = pow_eta_T * pm[aa].x - acc[aa][0];
        nm.y = pow_eta_T * pm[aa].y - acc[aa][1];
        nm.z = pow_eta_T * pm[aa].z - acc[aa][2];
        nm.w = pow_eta_T * pm[aa].w - acc[aa][3];
        wn.x = beta_total * pw[aa].x + nm.x;
        wn.y = beta_total * pw[aa].y + nm.y;
        wn.z = beta_total * pw[aa].z + nm.z;
        wn.w = beta_total * pw[aa].w + nm.w;
        *reinterpret_cast<float4*>(mW_new + o * D + i) = nm;
        *reinterpret_cast<float4*>(W_new + o * D + i) = wn;
    }

    // ---- b epilogue (once per o-tile) ----
    if (iT == 0 && tid < 64) {
        float S = 0.f;
        for (int t = 0; t < T; ++t) S += sC[t] * sErr[t][tid];
        const int o = obase + tid;
        const float nmb = pow_eta_T * mb[o] - 2.f * S - 2.f * Csum * sB0[tid];
        mb_new[o] = nmb;
        b_new[o]  = beta_total * sB0[tid] + nmb;
    }

    // ---- losses partial (once per o-tile); losses zeroed by k1 ----
    if (iT == 1 && tid < 256) {
        const int t = tid >> 1, h = tid & 1;
        float L = 0.f;
        #pragma unroll 8
        for (int oo = 0; oo < 32; ++oo) {
            const int o = ((h * 32 + oo) + t) & 63;   // skew to dodge bank aliasing
            const float e = sErr[t][o] + sB0[o];
            L += e * e;
        }
        L += __shfl_xor(L, 1, 64);
        if (h == 0) atomicAdd(losses + t, L * (1.f / 768.f));
    }
}

extern "C" void kernel_launch(void* const* d_in, const int* in_sizes, int n_in,
                              void* d_out, int out_size, void* d_ws, size_t ws_size,
                              hipStream_t stream) {
    const float* W      = (const float*)d_in[0];
    const float* bparam = (const float*)d_in[1];
    const float* keys   = (const float*)d_in[2];
    const float* values = (const float*)d_in[3];
    const float* mW     = (const float*)d_in[4];
    const float* mb     = (const float*)d_in[5];

    float* out = (float*)d_out;
    float* W_new  = out;               // 768*768
    float* b_new  = out + 589824;      // 768
    float* mW_new = out + 590592;      // 768*768
    float* mb_new = out + 1180416;     // 768
    float* losses = out + 1181184;     // 128

    float* Ppart = (float*)d_ws;       // [12][8][128][64] floats = 3.1 MB

    double cs = 0.0;
    for (int t = 0; t < T; ++t) cs += 0.01 * pow(0.891, 127 - t);
    const float pow_eta_T  = (float)pow(0.9, 128);
    const float beta_total = (float)pow(0.99, 128);
    const float Csum = (float)cs;

    k1_pgemm<<<dim3(12, KC), 512, 0, stream>>>(W, keys, Ppart, losses);
    k2_main<<<144, 512, 0, stream>>>(Ppart, values, keys, W, mW, bparam, mb,
                                     W_new, b_new, mW_new, mb_new, losses,
                                     pow_eta_T, beta_total, Csum);
}

// Round 7
// 85.631 us; speedup vs baseline: 1.5023x; 1.0220x over previous
//
#include <hip/hip_runtime.h>
#include <math.h>

#define D 768
#define T 128
#define KC 16            // split-K chunks for GEMM1
#define CHUNKK (D / KC)  // 48
#define NSUB (CHUNKK / 16) // 3 sub-chunks of 16

// ln(0.9*0.99) = ln(0.891)
#define LN_ETA_DECAY (-0.11541085151132775f)

// ---------------------------------------------------------------------------
// XCD-locality scheme (both kernels, grid = 256, assumes round-robin
// blockIdx->XCD = blockIdx%8; wrong mapping costs speed only):
//   o-tile j is owned by XCD j%8. XCDs 0-3 own two o-tiles (j, j+8),
//   XCDs 4-7 own one. All k1 producer chunks AND all k2 consumer blocks of
//   an o-tile run on its XCD, so the Ppart tile (512 KB) stays in that
//   XCD's L2 for the 12x redundant reduce read.
// ---------------------------------------------------------------------------

// K1: split-K partial GEMM  P = keys @ W^T  (M=128 t, N=768 o, K=768)
// 192 active blocks (of 256), 256 threads, per-thread 8t x 4o, K-chunk 48.
// LDS cost/CU: 48k x 3 ds_read_b128 x 4 waves ~ 2.9 us (was 7.7 at 4x4/512).
// Ppart layout [oTile][kc][t][64]: contiguous 32 KB tile per block.
__global__ __launch_bounds__(256) void k1_pgemm(
    const float* __restrict__ W,
    const float* __restrict__ keys,
    float* __restrict__ Ppart,
    float* __restrict__ losses)
{
    __shared__ float sKt[16][132];  // [k][t], pitch 132
    __shared__ float sWo[16][68];   // [k][o], pitch 68

    const int b = blockIdx.x;
    const int xcd = b & 7, slot = b >> 3;   // slot 0..31
    int bx, by;
    if (slot < 16) { bx = xcd; by = slot; }
    else { if (xcd >= 4) return; bx = 8 + xcd; by = slot - 16; }

    const int obase = bx * 64;
    const int kbase = by * CHUNKK;
    const int tid = threadIdx.x;
    const int ty = tid >> 4;   // t-group (8 t's)
    const int tx = tid & 15;   // o-group (4 o's)
    const int t0 = tid >> 2;   // staging row (0..63)
    const int q0 = tid & 3;    // staging float4-col (0..3)

    if (b == 0 && tid < T) losses[tid] = 0.f;

    float acc[8][4];
    #pragma unroll
    for (int j = 0; j < 8; ++j)
        #pragma unroll
        for (int n = 0; n < 4; ++n) acc[j][n] = 0.f;

    // prologue: load sub-chunk 0 into regs
    float4 gk0 = *reinterpret_cast<const float4*>(keys + t0 * D + kbase + q0 * 4);
    float4 gk1 = *reinterpret_cast<const float4*>(keys + (t0 + 64) * D + kbase + q0 * 4);
    float4 gw  = *reinterpret_cast<const float4*>(W + (obase + t0) * D + kbase + q0 * 4);

    for (int c = 0; c < NSUB; ++c) {
        // regs -> LDS (transposed to k-major)
        sKt[q0 * 4 + 0][t0] = gk0.x;
        sKt[q0 * 4 + 1][t0] = gk0.y;
        sKt[q0 * 4 + 2][t0] = gk0.z;
        sKt[q0 * 4 + 3][t0] = gk0.w;
        sKt[q0 * 4 + 0][t0 + 64] = gk1.x;
        sKt[q0 * 4 + 1][t0 + 64] = gk1.y;
        sKt[q0 * 4 + 2][t0 + 64] = gk1.z;
        sKt[q0 * 4 + 3][t0 + 64] = gk1.w;
        sWo[q0 * 4 + 0][t0] = gw.x;
        sWo[q0 * 4 + 1][t0] = gw.y;
        sWo[q0 * 4 + 2][t0] = gw.z;
        sWo[q0 * 4 + 3][t0] = gw.w;
        __syncthreads();

        // issue NEXT sub-chunk's loads (consumed at next iteration's store)
        if (c + 1 < NSUB) {
            const int kb = kbase + (c + 1) * 16;
            gk0 = *reinterpret_cast<const float4*>(keys + t0 * D + kb + q0 * 4);
            gk1 = *reinterpret_cast<const float4*>(keys + (t0 + 64) * D + kb + q0 * 4);
            gw  = *reinterpret_cast<const float4*>(W + (obase + t0) * D + kb + q0 * 4);
        }

        #pragma unroll
        for (int k = 0; k < 16; ++k) {
            float4 a0 = *reinterpret_cast<const float4*>(&sKt[k][ty * 8]);
            float4 a1 = *reinterpret_cast<const float4*>(&sKt[k][ty * 8 + 4]);
            float4 bb = *reinterpret_cast<const float4*>(&sWo[k][tx * 4]);
            const float av[8] = { a0.x, a0.y, a0.z, a0.w, a1.x, a1.y, a1.z, a1.w };
            const float bv[4] = { bb.x, bb.y, bb.z, bb.w };
            #pragma unroll
            for (int j = 0; j < 8; ++j)
                #pragma unroll
                for (int n = 0; n < 4; ++n) acc[j][n] += av[j] * bv[n];
        }
        __syncthreads();
    }

    // contiguous 32 KB tile: Ppart[bx][by][t][0..63]
    float* outp = Ppart + (bx * KC + by) * (T * 64);
    #pragma unroll
    for (int j = 0; j < 8; ++j) {
        const int t = ty * 8 + j;
        float4 v = { acc[j][0], acc[j][1], acc[j][2], acc[j][3] };
        *reinterpret_cast<float4*>(outp + t * 64 + tx * 4) = v;
    }
}

// K2: fused reduce + GEMM2 + epilogues. 144 active blocks (of 256), 256 thr.
// sErr = sum_kc Ppart[oT][kc] - values (XCD-local L2 reads), then GEMM2
// G = errW^T @ (2c*keys) at 4o x 4i per thread with mW/W register-prefetched
// epilogue; iT==0 emits b_new/mb_new; iT==1 adds loss partials.
__global__ __launch_bounds__(256) void k2_main(
    const float* __restrict__ Ppart,
    const float* __restrict__ values,
    const float* __restrict__ keys,
    const float* __restrict__ W,
    const float* __restrict__ mW,
    const float* __restrict__ bparam,
    const float* __restrict__ mb,
    float* __restrict__ W_new,
    float* __restrict__ b_new,
    float* __restrict__ mW_new,
    float* __restrict__ mb_new,
    float* __restrict__ losses,
    float pow_eta_T, float beta_total, float Csum)
{
    __shared__ float sErr[T][64];   // errW[t, o-local]
    __shared__ float sKs[T][64];    // 2*c[t]*keys[t, i-local]
    __shared__ float sC[T];         // c[t]
    __shared__ float sB0[64];       // bparam[o-local]

    const int b = blockIdx.x;
    const int xcd = b & 7, slot = b >> 3;   // slot 0..31
    int oT, iT;
    if (slot < 12) { oT = xcd; iT = slot; }
    else if (xcd < 4 && slot >= 16 && slot < 28) { oT = 8 + xcd; iT = slot - 16; }
    else return;

    const int obase = oT * 64, ibase = iT * 64;
    const int tid = threadIdx.x;
    const int ty = tid >> 4, tx = tid & 15;   // o-group, i-group

    // ---- epilogue prefetch: issue mW/W loads NOW, consume after GEMM2 ----
    float4 pm[4], pw[4];
    #pragma unroll
    for (int aa = 0; aa < 4; ++aa) {
        const int o = obase + ty * 4 + aa;
        const int i = ibase + tx * 4;
        pm[aa] = *reinterpret_cast<const float4*>(mW + o * D + i);
        pw[aa] = *reinterpret_cast<const float4*>(W + o * D + i);
    }

    if (tid < T)  sC[tid]  = 0.01f * __expf((float)(127 - tid) * LN_ETA_DECAY);
    if (tid < 64) sB0[tid] = bparam[obase + tid];

    // ---- stage sKs = 2*c[t]*keys[t, i-tile] ----
    #pragma unroll
    for (int p = 0; p < 8; ++p) {
        const int idx = tid + p * 256;
        const int t = idx >> 4, q = idx & 15;
        const float c2 = 2.f * 0.01f * __expf((float)(127 - t) * LN_ETA_DECAY);
        float4 kv = *reinterpret_cast<const float4*>(keys + t * D + ibase + q * 4);
        kv.x *= c2; kv.y *= c2; kv.z *= c2; kv.w *= c2;
        *reinterpret_cast<float4*>(&sKs[t][q * 4]) = kv;
    }

    // ---- stage sErr = sum_kc Ppart[oT][kc] - values (fused k15; L2-local) ----
    const float* Pp = Ppart + oT * (KC * T * 64);
    #pragma unroll
    for (int p = 0; p < 8; ++p) {
        const int idx = tid + p * 256;
        const int t = idx >> 4, q = idx & 15;
        float4 vv = *reinterpret_cast<const float4*>(values + t * D + obase + q * 4);
        float4 s = { -vv.x, -vv.y, -vv.z, -vv.w };
        #pragma unroll
        for (int kc = 0; kc < KC; ++kc) {
            float4 v = *reinterpret_cast<const float4*>(Pp + kc * (T * 64) + t * 64 + q * 4);
            s.x += v.x; s.y += v.y; s.z += v.z; s.w += v.w;
        }
        *reinterpret_cast<float4*>(&sErr[t][q * 4]) = s;
    }
    __syncthreads();

    // ---- GEMM2: 4o x 4i per thread ----
    float acc[4][4];
    #pragma unroll
    for (int a = 0; a < 4; ++a)
        #pragma unroll
        for (int n = 0; n < 4; ++n) acc[a][n] = 0.f;

    #pragma unroll 4
    for (int t = 0; t < T; ++t) {
        float4 a = *reinterpret_cast<const float4*>(&sErr[t][ty * 4]);
        float4 bb = *reinterpret_cast<const float4*>(&sKs[t][tx * 4]);
        const float av[4] = { a.x, a.y, a.z, a.w };
        const float bv[4] = { bb.x, bb.y, bb.z, bb.w };
        #pragma unroll
        for (int aa = 0; aa < 4; ++aa)
            #pragma unroll
            for (int nn = 0; nn < 4; ++nn) acc[aa][nn] += av[aa] * bv[nn];
    }

    // ---- W / mW epilogue from prefetched regs ----
    #pragma unroll
    for (int aa = 0; aa < 4; ++aa) {
        const int o = obase + ty * 4 + aa;
        const int i = ibase + tx * 4;
        float4 nm, wn;
        nm.x = pow_eta_T * pm[aa].x - acc[aa][0];
        nm.y = pow_eta_T * pm[aa].y - acc[aa][1];
        nm.z = pow_eta_T * pm[aa].z - acc[aa][2];
        nm.w = pow_eta_T * pm[aa].w - acc[aa][3];
        wn.x = beta_total * pw[aa].x + nm.x;
        wn.y = beta_total * pw[aa].y + nm.y;
        wn.z = beta_total * pw[aa].z + nm.z;
        wn.w = beta_total * pw[aa].w + nm.w;
        *reinterpret_cast<float4*>(mW_new + o * D + i) = nm;
        *reinterpret_cast<float4*>(W_new + o * D + i) = wn;
    }

    // ---- b epilogue (once per o-tile) ----
    if (iT == 0 && tid < 64) {
        float S = 0.f;
        for (int t = 0; t < T; ++t) S += sC[t] * sErr[t][tid];
        const int o = obase + tid;
        const float nmb = pow_eta_T * mb[o] - 2.f * S - 2.f * Csum * sB0[tid];
        mb_new[o] = nmb;
        b_new[o]  = beta_total * sB0[tid] + nmb;
    }

    // ---- losses partial (once per o-tile); losses zeroed by k1 ----
    if (iT == 1) {
        const int t = tid >> 1, h = tid & 1;
        float L = 0.f;
        #pragma unroll 8
        for (int oo = 0; oo < 32; ++oo) {
            const int o = ((h * 32 + oo) + t) & 63;   // skew to dodge bank aliasing
            const float e = sErr[t][o] + sB0[o];
            L += e * e;
        }
        L += __shfl_xor(L, 1, 64);
        if (h == 0) atomicAdd(losses + t, L * (1.f / 768.f));
    }
}

extern "C" void kernel_launch(void* const* d_in, const int* in_sizes, int n_in,
                              void* d_out, int out_size, void* d_ws, size_t ws_size,
                              hipStream_t stream) {
    const float* W      = (const float*)d_in[0];
    const float* bparam = (const float*)d_in[1];
    const float* keys   = (const float*)d_in[2];
    const float* values = (const float*)d_in[3];
    const float* mW     = (const float*)d_in[4];
    const float* mb     = (const float*)d_in[5];

    float* out = (float*)d_out;
    float* W_new  = out;               // 768*768
    float* b_new  = out + 589824;      // 768
    float* mW_new = out + 590592;      // 768*768
    float* mb_new = out + 1180416;     // 768
    float* losses = out + 1181184;     // 128

    float* Ppart = (float*)d_ws;       // [12][16][128][64] floats = 6.3 MB

    double cs = 0.0;
    for (int t = 0; t < T; ++t) cs += 0.01 * pow(0.891, 127 - t);
    const float pow_eta_T  = (float)pow(0.9, 128);
    const float beta_total = (float)pow(0.99, 128);
    const float Csum = (float)cs;

    k1_pgemm<<<256, 256, 0, stream>>>(W, keys, Ppart, losses);
    k2_main<<<256, 256, 0, stream>>>(Ppart, values, keys, W, mW, bparam, mb,
                                     W_new, b_new, mW_new, mb_new, losses,
                                     pow_eta_T, beta_total, Csum);
}